// Round 1
// baseline (5809.330 us; speedup 1.0000x reference)
//
#include <hip/hip_runtime.h>
#include <math.h>

#define PLANE 884736          // 96*96*96
#define NPLANES 64            // B*C = 2*32

// ---------------------------------------------------------------------------
// Prep: expert MLPs (mod[4][27], biasK[4][32]), scaled cluster centers,
// weight transposes [o][c][s] -> [c][s][o] for SGPR-friendly access.
// ---------------------------------------------------------------------------
__global__ void prep_kernel(
    const float* __restrict__ cc,
    const float* __restrict__ proj_w,
    const float* __restrict__ base_w,
    const float* __restrict__ w1, const float* __restrict__ b1,
    const float* __restrict__ w2, const float* __restrict__ b2,
    const float* __restrict__ w3, const float* __restrict__ b3,
    const float* __restrict__ g1, const float* __restrict__ gb1,
    const float* __restrict__ g2, const float* __restrict__ gb2,
    float* __restrict__ wT1, float* __restrict__ wT2,
    float* __restrict__ modv, float* __restrict__ biasK,
    float* __restrict__ ccs)
{
    __shared__ float ccl[4][32];
    __shared__ float h1s[4][128];
    __shared__ float h2s[4][128];
    __shared__ float bhs[4][64];
    const int tid = threadIdx.x;

    if (tid < 128) {
        float v = cc[tid];
        ccl[tid >> 5][tid & 31] = v;
        ccs[tid] = v * 0.17677669529663687f;   // 1/sqrt(32)
    }
    __syncthreads();

    // h1 = relu(cc @ w1^T + b1)  [4][128]
    for (int r = 0; r < 2; ++r) {
        int id = tid + r * 256;
        int k = id >> 7, i = id & 127;
        float s = b1[i];
        for (int c = 0; c < 32; ++c) s = fmaf(ccl[k][c], w1[i * 32 + c], s);
        h1s[k][i] = fmaxf(s, 0.f);
    }
    __syncthreads();

    // h2 = relu(h1 @ w2^T + b2)  [4][128]
    for (int r = 0; r < 2; ++r) {
        int id = tid + r * 256;
        int k = id >> 7, i = id & 127;
        float s = b2[i];
        for (int j = 0; j < 128; ++j) s = fmaf(h1s[k][j], w2[i * 128 + j], s);
        h2s[k][i] = fmaxf(s, 0.f);
    }
    __syncthreads();

    // mod = sigmoid(h2 @ w3^T + b3)  [4][27]
    if (tid < 108) {
        int k = tid / 27, t = tid - k * 27;
        float s = b3[t];
        for (int j = 0; j < 128; ++j) s = fmaf(h2s[k][j], w3[t * 128 + j], s);
        modv[tid] = 1.f / (1.f + expf(-s));
    }

    // bias path: bh = relu(cc @ g1^T + gb1)  [4][64]
    {
        int k = tid >> 6, i = tid & 63;
        float s = gb1[i];
        for (int c = 0; c < 32; ++c) s = fmaf(ccl[k][c], g1[i * 32 + c], s);
        bhs[k][i] = fmaxf(s, 0.f);
    }
    __syncthreads();

    // biasK = bh @ g2^T + gb2  [4][32]
    if (tid < 128) {
        int k = tid >> 5, o = tid & 31;
        float s = gb2[o];
        for (int i = 0; i < 64; ++i) s = fmaf(bhs[k][i], g2[o * 64 + i], s);
        biasK[tid] = s;
    }

    // transpose weights: src [o][c][s] flat -> dst [(c*27+s)*32 + o]
    for (int idx = tid; idx < 27648; idx += 256) {
        int o = idx / 864;
        int rem = idx - o * 864;
        int c = rem / 27;
        int s = rem - c * 27;
        int dst = (c * 27 + s) * 32 + o;
        wT1[dst] = proj_w[idx];
        wT2[dst] = base_w[idx];
    }
}

// ---------------------------------------------------------------------------
// Direct 3^3 conv, 32ch -> 32ch. Tile 4x8x8 voxels, all 32 input channels in
// LDS (6*10*10*32 floats = 76.8 KB -> 2 blocks/CU). Each thread: 1 voxel,
// 32 output-channel accumulators. Weights via uniform (scalar) loads.
// MODE 0: plain conv (proj_in). MODE 1: effmod-modulated conv + mixed bias.
// ---------------------------------------------------------------------------
template <int MODE>
__global__ __launch_bounds__(256, 2) void conv_kernel(
    const float* __restrict__ in,      // [B*32][PLANE]
    const float* __restrict__ wT,      // [32][27][32]
    const float* __restrict__ cw,      // [B*4][PLANE]    (MODE 1)
    const float* __restrict__ modv,    // [4][27]         (MODE 1)
    const float* __restrict__ biasK,   // [4][32]         (MODE 1)
    float* __restrict__ out)           // [B*32][PLANE]
{
    __shared__ float lx[32 * 600];     // [c][zz6][yy10][xx10]

    const int b = blockIdx.y;
    int bx = blockIdx.x;
    const int tx = bx % 12; bx /= 12;
    const int ty = bx % 12; bx /= 12;
    const int tz = bx;                 // 0..23
    const int x0 = tx * 8, y0 = ty * 8, z0 = tz * 4;
    const int tid = threadIdx.x;

    // ---- stage input tile + halo (zero padded) ----
    const float* inb = in + (size_t)b * 32 * PLANE;
    for (int idx = tid; idx < 19200; idx += 256) {
        int c = idx / 600;
        int r = idx - c * 600;
        int zz = r / 100; r -= zz * 100;
        int yy = r / 10;
        int xx = r - yy * 10;
        int gz = z0 + zz - 1, gy = y0 + yy - 1, gx = x0 + xx - 1;
        float v = 0.f;
        if ((unsigned)gz < 96u && (unsigned)gy < 96u && (unsigned)gx < 96u)
            v = inb[(size_t)c * PLANE + (size_t)(gz * 96 + gy) * 96 + gx];
        lx[idx] = v;
    }
    __syncthreads();

    const int vx = tid & 7, vy = (tid >> 3) & 7, vz = tid >> 6;
    const size_t pvox = ((size_t)(z0 + vz) * 96 + (y0 + vy)) * 96 + (x0 + vx);

    float acc[32];
#pragma unroll
    for (int o = 0; o < 32; ++o) acc[o] = 0.f;

    float em[27];
    float cwv[4];
    if (MODE == 1) {
#pragma unroll
        for (int k = 0; k < 4; ++k)
            cwv[k] = cw[((size_t)b * 4 + k) * PLANE + pvox];
#pragma unroll
        for (int s = 0; s < 27; ++s) {
            float e = 0.f;
#pragma unroll
            for (int k = 0; k < 4; ++k) e = fmaf(cwv[k], modv[k * 27 + s], e);
            em[s] = e;
        }
    }

    // ---- main loop ----
#pragma unroll 1
    for (int c = 0; c < 32; ++c) {
        const float* lc = &lx[c * 600];
#pragma unroll
        for (int dz = 0; dz < 3; ++dz)
#pragma unroll
            for (int dy = 0; dy < 3; ++dy) {
                const float* lrow = &lc[(vz + dz) * 100 + (vy + dy) * 10 + vx];
#pragma unroll
                for (int dx = 0; dx < 3; ++dx) {
                    float xv = lrow[dx];
                    const int s = (dz * 3 + dy) * 3 + dx;
                    if (MODE == 1) xv *= em[s];
                    const float* wr = &wT[(c * 27 + s) * 32];   // uniform -> SGPR
#pragma unroll
                    for (int o = 0; o < 32; ++o)
                        acc[o] = fmaf(wr[o], xv, acc[o]);
                }
            }
    }

    if (MODE == 1) {
#pragma unroll
        for (int o = 0; o < 32; ++o) {
            float bo = 0.f;
#pragma unroll
            for (int k = 0; k < 4; ++k) bo = fmaf(cwv[k], biasK[k * 32 + o], bo);
            acc[o] += bo;
        }
    }

    float* outb = out + (size_t)b * 32 * PLANE + pvox;
#pragma unroll
    for (int o = 0; o < 32; ++o) outb[(size_t)o * PLANE] = acc[o];
}

// ---------------------------------------------------------------------------
// Two-stage per-plane mean/var reduction (no atomics, poison-safe).
// ---------------------------------------------------------------------------
__global__ void reduce_partial(const float* __restrict__ src,
                               float* __restrict__ part)  // [64][8][2]
{
    const int plane = blockIdx.y;
    const int chunk = blockIdx.x;     // 0..7
    const float4* p4 = (const float4*)(src + (size_t)plane * PLANE) + (size_t)chunk * 27648;
    float s = 0.f, sq = 0.f;
    for (int i = threadIdx.x; i < 27648; i += 256) {
        float4 v = p4[i];
        s += v.x + v.y + v.z + v.w;
        sq = fmaf(v.x, v.x, sq); sq = fmaf(v.y, v.y, sq);
        sq = fmaf(v.z, v.z, sq); sq = fmaf(v.w, v.w, sq);
    }
#pragma unroll
    for (int off = 32; off > 0; off >>= 1) {
        s  += __shfl_down(s, off, 64);
        sq += __shfl_down(sq, off, 64);
    }
    __shared__ float ls[4], lq[4];
    const int wid = threadIdx.x >> 6, lane = threadIdx.x & 63;
    if (lane == 0) { ls[wid] = s; lq[wid] = sq; }
    __syncthreads();
    if (threadIdx.x == 0) {
        for (int i = 1; i < 4; ++i) { s += ls[i]; sq += lq[i]; }
        part[(plane * 8 + chunk) * 2]     = s;
        part[(plane * 8 + chunk) * 2 + 1] = sq;
    }
}

__global__ void reduce_final(const float* __restrict__ part,
                             float* __restrict__ stats)   // [64][2] = mean, rstd
{
    const int p = threadIdx.x;
    if (p < NPLANES) {
        double s = 0.0, sq = 0.0;
        for (int ch = 0; ch < 8; ++ch) {
            s  += (double)part[(p * 8 + ch) * 2];
            sq += (double)part[(p * 8 + ch) * 2 + 1];
        }
        double mean = s / (double)PLANE;
        double var  = sq / (double)PLANE - mean * mean;
        if (var < 0.0) var = 0.0;
        stats[p * 2]     = (float)mean;
        stats[p * 2 + 1] = rsqrtf((float)var + 1e-5f);
    }
}

// ---------------------------------------------------------------------------
// Fused InstanceNorm + LeakyReLU + cluster softmax. Reads raw conv1 (d_out),
// writes xp (ws) and cw (ws).
// ---------------------------------------------------------------------------
__global__ __launch_bounds__(256) void norm_softmax_kernel(
    const float* __restrict__ y1,      // [B*32][PLANE] raw conv1
    const float* __restrict__ stats,   // [64][2]
    const float* __restrict__ ccs,     // [4][32] scaled centers
    float* __restrict__ xp,            // [B*32][PLANE]
    float* __restrict__ cwout)         // [B*4][PLANE]
{
    const int b = blockIdx.y;
    const size_t p = (size_t)blockIdx.x * 256 + threadIdx.x;
    const float* yb = y1 + (size_t)b * 32 * PLANE + p;
    float* xpb = xp + (size_t)b * 32 * PLANE + p;

    float s0 = 0.f, s1 = 0.f, s2 = 0.f, s3 = 0.f;
#pragma unroll
    for (int c = 0; c < 32; ++c) {
        float v = yb[(size_t)c * PLANE];
        const float m = stats[(b * 32 + c) * 2];
        const float r = stats[(b * 32 + c) * 2 + 1];
        float xn = (v - m) * r;
        xn = xn >= 0.f ? xn : 0.1f * xn;
        xpb[(size_t)c * PLANE] = xn;
        s0 = fmaf(xn, ccs[c],      s0);
        s1 = fmaf(xn, ccs[32 + c], s1);
        s2 = fmaf(xn, ccs[64 + c], s2);
        s3 = fmaf(xn, ccs[96 + c], s3);
    }
    float mx = fmaxf(fmaxf(s0, s1), fmaxf(s2, s3));
    float e0 = expf(s0 - mx), e1 = expf(s1 - mx), e2 = expf(s2 - mx), e3 = expf(s3 - mx);
    float inv = 1.f / (e0 + e1 + e2 + e3);
    float* cwb = cwout + (size_t)b * 4 * PLANE + p;
    cwb[0]          = e0 * inv;
    cwb[PLANE]      = e1 * inv;
    cwb[2 * PLANE]  = e2 * inv;
    cwb[3 * PLANE]  = e3 * inv;
}

// ---------------------------------------------------------------------------
// Final: out = lrelu(inorm(out_raw)) + x   (in place on d_out)
// ---------------------------------------------------------------------------
__global__ __launch_bounds__(256) void finalize_kernel(
    float* __restrict__ out,
    const float* __restrict__ x,
    const float* __restrict__ stats)
{
    const int plane = blockIdx.y;      // 0..63
    const float m = stats[plane * 2];
    const float r = stats[plane * 2 + 1];
    const size_t base = (size_t)plane * PLANE + (size_t)blockIdx.x * 1024 + threadIdx.x * 4;
    float4 v  = *(const float4*)(out + base);
    float4 xi = *(const float4*)(x + base);
    float4 o;
    float t;
    t = (v.x - m) * r; t = t >= 0.f ? t : 0.1f * t; o.x = t + xi.x;
    t = (v.y - m) * r; t = t >= 0.f ? t : 0.1f * t; o.y = t + xi.y;
    t = (v.z - m) * r; t = t >= 0.f ? t : 0.1f * t; o.z = t + xi.z;
    t = (v.w - m) * r; t = t >= 0.f ? t : 0.1f * t; o.w = t + xi.w;
    *(float4*)(out + base) = o;
}

// ---------------------------------------------------------------------------
extern "C" void kernel_launch(void* const* d_in, const int* in_sizes, int n_in,
                              void* d_out, int out_size, void* d_ws, size_t ws_size,
                              hipStream_t stream)
{
    const float* x      = (const float*)d_in[0];
    const float* cc     = (const float*)d_in[1];
    const float* proj_w = (const float*)d_in[2];
    const float* base_w = (const float*)d_in[3];
    const float* wm_w1  = (const float*)d_in[4];
    const float* wm_b1  = (const float*)d_in[5];
    const float* wm_w2  = (const float*)d_in[6];
    const float* wm_b2  = (const float*)d_in[7];
    const float* wm_w3  = (const float*)d_in[8];
    const float* wm_b3  = (const float*)d_in[9];
    const float* bg_w1  = (const float*)d_in[10];
    const float* bg_b1  = (const float*)d_in[11];
    const float* bg_w2  = (const float*)d_in[12];
    const float* bg_b2  = (const float*)d_in[13];
    float* out = (float*)d_out;

    // workspace carve (floats)
    float* xp     = (float*)d_ws;            // 2*32*PLANE = 56,623,104
    float* cw     = xp + (size_t)56623104;   // 2*4*PLANE  =  7,077,888
    float* wT1    = cw + (size_t)7077888;    // 27,648
    float* wT2    = wT1 + 27648;             // 27,648
    float* modv   = wT2 + 27648;             // 128 (108 used)
    float* biasK  = modv + 128;              // 128
    float* ccs    = biasK + 128;             // 128
    float* part   = ccs + 128;               // 64*8*2 = 1024
    float* stats1 = part + 1024;             // 128
    float* stats2 = stats1 + 128;            // 128

    // 1. prep (tiny)
    prep_kernel<<<1, 256, 0, stream>>>(cc, proj_w, base_w,
                                       wm_w1, wm_b1, wm_w2, wm_b2, wm_w3, wm_b3,
                                       bg_w1, bg_b1, bg_w2, bg_b2,
                                       wT1, wT2, modv, biasK, ccs);

    const dim3 cgrid(3456, 2);   // 24z * 12y * 12x tiles, B=2

    // 2. conv1 -> d_out (raw)
    conv_kernel<0><<<cgrid, 256, 0, stream>>>(x, wT1, nullptr, nullptr, nullptr, out);

    // 3-4. instance-norm stats of conv1
    reduce_partial<<<dim3(8, NPLANES), 256, 0, stream>>>(out, part);
    reduce_final<<<1, 64, 0, stream>>>(part, stats1);

    // 5. norm + lrelu + softmax -> xp, cw
    norm_softmax_kernel<<<cgrid, 256, 0, stream>>>(out, stats1, ccs, xp, cw);

    // 6. modulated conv2 -> d_out (raw)
    conv_kernel<1><<<cgrid, 256, 0, stream>>>(xp, wT2, cw, modv, biasK, out);

    // 7-8. instance-norm stats of conv2
    reduce_partial<<<dim3(8, NPLANES), 256, 0, stream>>>(out, part);
    reduce_final<<<1, 64, 0, stream>>>(part, stats2);

    // 9. final norm + lrelu + residual (in place)
    finalize_kernel<<<dim3(864, NPLANES), 256, 0, stream>>>(out, x, stats2);
}